// Round 13
// baseline (3763.501 us; speedup 1.0000x reference)
//
#include <hip/hip_runtime.h>

#define TSTEPS 2048
#define PPB 16          // paths per block
#define NT 256          // 4 waves; wave wv = column tile; each wave does BOTH MLPs
#define KAPPA 2.72f
#define THETA -3.5f

typedef _Float16 half8 __attribute__((ext_vector_type(8)));
typedef __fp16 fp16x2 __attribute__((ext_vector_type(2)));
typedef float f32x4 __attribute__((ext_vector_type(4)));

__device__ __forceinline__ f32x4 mm(half8 a, half8 b, f32x4 c) {
    return __builtin_amdgcn_mfma_f32_16x16x32_f16(a, b, c, 0, 0, 0);
}
__device__ __forceinline__ void wsplit(float v, _Float16& h, _Float16& l) {
    h = (_Float16)v; l = (_Float16)(v - (float)h);
}
__device__ __forceinline__ float clamp9(float x) {
    return fminf(fmaxf(x, -9.0f), 9.0f);     // v_med3_f32; tanh(9)=1-2e-8
}

// 4 tanh with ONE v_rcp. Inputs clamped to [-9,9] so a_i = 1+e^{2x} <= 6.6e7
// and the 4-way product <= 1.9e31 << f32 max (no overflow possible).
__device__ __forceinline__ f32x4 tanh4(f32x4 x) {
    const float a0 = __expf(2.0f * clamp9(x[0])) + 1.0f;
    const float a1 = __expf(2.0f * clamp9(x[1])) + 1.0f;
    const float a2 = __expf(2.0f * clamp9(x[2])) + 1.0f;
    const float a3 = __expf(2.0f * clamp9(x[3])) + 1.0f;
    const float p01 = a0 * a1, p23 = a2 * a3;
    const float R = __builtin_amdgcn_rcpf(p01 * p23);
    const float r01 = p23 * R;   // 1/(a0*a1)
    const float r23 = p01 * R;   // 1/(a2*a3)
    f32x4 t;
    t[0] = fmaf(-2.0f * a1, r01, 1.0f);
    t[1] = fmaf(-2.0f * a0, r01, 1.0f);
    t[2] = fmaf(-2.0f * a3, r23, 1.0f);
    t[3] = fmaf(-2.0f * a2, r23, 1.0f);
    return t;
}

// LDS f16 activation rows: [row 0..15][slot 0..7][elem 0..7], slot = chunk ^ (row&7).

__global__ __launch_bounds__(NT, 2) void sim_kernel(
    const float* __restrict__ init_var, const float* __restrict__ dtp,
    const float* __restrict__ dwg,
    const float* __restrict__ dW0, const float* __restrict__ dB0,
    const float* __restrict__ dW1, const float* __restrict__ dB1,
    const float* __restrict__ dW2, const float* __restrict__ dB2,
    const float* __restrict__ dW3, const float* __restrict__ dB3,
    const float* __restrict__ fW0, const float* __restrict__ fB0,
    const float* __restrict__ fW1, const float* __restrict__ fB1,
    const float* __restrict__ fW2, const float* __restrict__ fB2,
    const float* __restrict__ fW3, const float* __restrict__ fB3,
    float* __restrict__ out)
{
    __shared__ __align__(16) _Float16 hA[2][1024];
    __shared__ __align__(16) _Float16 hB[2][1024];
    __shared__ __align__(16) _Float16 hC[2][1024];

    const int tid  = threadIdx.x;
    const int lane = tid & 63;
    const int wv   = tid >> 6;        // 0..3 column tile
    const int l15  = lane & 15;
    const int lg   = lane >> 4;       // 0..3
    const int col  = wv * 16 + l15;   // column this lane supplies (B) / owns (C)
    const int q    = l15 & 7;

    const int roff0 = l15 * 64 + ((lg ^ q) << 3);         // chunks 0-3 (K 0..31)
    const int roff1 = l15 * 64 + (((4 + lg) ^ q) << 3);   // chunks 4-7 (K 32..63)
    int woff[4];
#pragma unroll
    for (int r = 0; r < 4; ++r) {
        const int wrow = lg * 4 + r;
        woff[r] = wrow * 64 + ((((col >> 3) ^ (wrow & 7))) << 3) + (col & 7);
    }

    // ---------------- B-fragments: 16 half8 = 64 VGPR ----------------
    half8 bd0h, bd0l, bf0h, bf0l;
#pragma unroll
    for (int i = 0; i < 8; ++i) {
        const int idx = (lg & 1) * 8 + i;
        const float vd = (idx < 15) ? dW0[col * 15 + idx] : 0.f;
        const float vf = (idx < 15) ? fW0[col * 15 + idx] : 0.f;
        _Float16 h, l;
        wsplit(vd, h, l); bd0h[i] = h; bd0l[i] = l;
        wsplit(vf, h, l); bf0h[i] = h; bf0l[i] = l;
    }
    half8 bd1h0, bd1h1, bd2h0, bd2h1;
    half8 bf1h0, bf1h1, bf2h0, bf2h1;
#pragma unroll
    for (int i = 0; i < 8; ++i) {
        const int ka = lg * 8 + i, kb = 32 + lg * 8 + i;
        bd1h0[i] = (_Float16)dW1[col * 64 + ka];
        bd1h1[i] = (_Float16)dW1[col * 64 + kb];
        bd2h0[i] = (_Float16)dW2[col * 64 + ka];
        bd2h1[i] = (_Float16)dW2[col * 64 + kb];
        bf1h0[i] = (_Float16)fW1[col * 64 + ka];
        bf1h1[i] = (_Float16)fW1[col * 64 + kb];
        bf2h0[i] = (_Float16)fW2[col * 64 + ka];
        bf2h1[i] = (_Float16)fW2[col * 64 + kb];
    }
    half8 w3d0, w3d1, w3f0, w3f1;
#pragma unroll
    for (int i = 0; i < 8; ++i) {
        const int ka = lg * 8 + i, kb = 32 + lg * 8 + i;
        w3d0[i] = (_Float16)dW3[ka];
        w3d1[i] = (_Float16)dW3[kb];
        w3f0[i] = (_Float16)fW3[ka];
        w3f1[i] = (_Float16)fW3[kb];
    }
    // Pin weight fragments against in-loop rematerialization.
    asm volatile("" : "+v"(bd0h), "+v"(bd0l), "+v"(bf0h), "+v"(bf0l));
    asm volatile("" : "+v"(bd1h0), "+v"(bd1h1), "+v"(bd2h0), "+v"(bd2h1));
    asm volatile("" : "+v"(bf1h0), "+v"(bf1h1), "+v"(bf2h0), "+v"(bf2h1));
    asm volatile("" : "+v"(w3d0), "+v"(w3d1), "+v"(w3f0), "+v"(w3f1));

    const float biasd0 = dB0[col], biasd1 = dB1[col], biasd2 = dB2[col];
    const float biasf0 = fB0[col], biasf1 = fB1[col], biasf2 = fB2[col];
    const float b3d = dB3[0], b3f = fB3[0];
    const float dt  = dtp[0];
    const float hdt  = 0.5f * dt;
    const float c6dt = dt * (1.0f / 6.0f);
    const float kdt  = KAPPA * dt;
    const float o0   = dt * dt;

    // ---------------- replicated per-lane state (p = l15) ----------------
    const int p = l15;
    const int path = blockIdx.x * PPB + p;
    const size_t pathT = (size_t)path * TSTEPS;
    const float* dwp = dwg + pathT;
    float iv = fminf(fmaxf(init_var[path], 0.01f), 1.5f);
    float lv = __logf(iv);
    float s1a0 = 0.f, s1a1 = 0.f;
    float s2a0 = 0.f, s2a1 = 0.f, s2a2 = 0.f, s2a3 = 0.f;
    float s3a0 = 0.f, s3a1 = 0.f, s3a2 = 0.f, s3a3 = 0.f;
    float s3a4 = 0.f, s3a5 = 0.f, s3a6 = 0.f, s3a7 = 0.f;

    const bool selHi = (lg & 1) != 0;   // lane's L0 A-frag covers x[8..15]
    const bool selLo = (lg & 2) != 0;   // lane's L0 A-frag carries the lo split

    union H8 { half8 v; fp16x2 p2[4]; uint4 u; };

    for (int t = 0; t < TSTEPS; ++t) {
        const float dwv = dwp[t];

        // ---- build L0 A-fragment in-register (pkrtz-packed hi/lo) ----
        half8 a0;
        {
            float xv[8];
            xv[0] = selHi ? s3a2 : s1a0;
            xv[1] = selHi ? s3a3 : s1a1;
            xv[2] = selHi ? s3a4 : s2a0;
            xv[3] = selHi ? s3a5 : s2a1;
            xv[4] = selHi ? s3a6 : s2a2;
            xv[5] = selHi ? s3a7 : s2a3;
            xv[6] = selHi ? (lv + 4.0f) : s3a0;
            xv[7] = selHi ? 0.f : s3a1;
            H8 hi, lo, a;
#pragma unroll
            for (int j = 0; j < 4; ++j)
                hi.p2[j] = __builtin_amdgcn_cvt_pkrtz(xv[2 * j], xv[2 * j + 1]);
#pragma unroll
            for (int j = 0; j < 4; ++j) {
                const float r0 = xv[2 * j]     - (float)hi.p2[j][0];
                const float r1 = xv[2 * j + 1] - (float)hi.p2[j][1];
                lo.p2[j] = __builtin_amdgcn_cvt_pkrtz(r0, r1);
            }
            a.u.x = selLo ? lo.u.x : hi.u.x;
            a.u.y = selLo ? lo.u.y : hi.u.y;
            a.u.z = selLo ? lo.u.z : hi.u.z;
            a.u.w = selLo ? lo.u.w : hi.u.w;
            a0 = a.v;
        }

        // ---- L0: x -> h0 (both MLPs, 2 MFMA each, exact hi/lo) ----
        {
            f32x4 cd = {biasd0, biasd0, biasd0, biasd0};
            f32x4 cf = {biasf0, biasf0, biasf0, biasf0};
            cd = mm(a0, bd0h, cd);  cf = mm(a0, bf0h, cf);
            cd = mm(a0, bd0l, cd);  cf = mm(a0, bf0l, cf);
            const f32x4 td = tanh4(cd), tf = tanh4(cf);
#pragma unroll
            for (int r = 0; r < 4; ++r) {
                hA[0][woff[r]] = (_Float16)td[r];
                hA[1][woff[r]] = (_Float16)tf[r];
            }
        }
        __syncthreads();

        // ---- L1: h0 -> h1 (f16 weights) ----
        {
            const half8 ad0 = *(const half8*)(&hA[0][roff0]);
            const half8 ad1 = *(const half8*)(&hA[0][roff1]);
            const half8 af0 = *(const half8*)(&hA[1][roff0]);
            const half8 af1 = *(const half8*)(&hA[1][roff1]);
            f32x4 cd = {biasd1, biasd1, biasd1, biasd1};
            f32x4 cf = {biasf1, biasf1, biasf1, biasf1};
            cd = mm(ad0, bd1h0, cd);  cf = mm(af0, bf1h0, cf);
            cd = mm(ad1, bd1h1, cd);  cf = mm(af1, bf1h1, cf);
            const f32x4 td = tanh4(cd), tf = tanh4(cf);
#pragma unroll
            for (int r = 0; r < 4; ++r) {
                hB[0][woff[r]] = (_Float16)td[r];
                hB[1][woff[r]] = (_Float16)tf[r];
            }
        }
        __syncthreads();

        // ---- L2: h1 -> h2 ----
        {
            const half8 ad0 = *(const half8*)(&hB[0][roff0]);
            const half8 ad1 = *(const half8*)(&hB[0][roff1]);
            const half8 af0 = *(const half8*)(&hB[1][roff0]);
            const half8 af1 = *(const half8*)(&hB[1][roff1]);
            f32x4 cd = {biasd2, biasd2, biasd2, biasd2};
            f32x4 cf = {biasf2, biasf2, biasf2, biasf2};
            cd = mm(ad0, bd2h0, cd);  cf = mm(af0, bf2h0, cf);
            cd = mm(ad1, bd2h1, cd);  cf = mm(af1, bf2h1, cf);
            const f32x4 td = tanh4(cd), tf = tanh4(cf);
#pragma unroll
            for (int r = 0; r < 4; ++r) {
                hC[0][woff[r]] = (_Float16)td[r];
                hC[1][woff[r]] = (_Float16)tf[r];
            }
        }
        __syncthreads();

        // ---- L3: od/of broadcast to all lanes via w3-replicated A ----
        float od, of;
        {
            const half8 bd0 = *(const half8*)(&hC[0][roff0]);
            const half8 bd1 = *(const half8*)(&hC[0][roff1]);
            const half8 bf0 = *(const half8*)(&hC[1][roff0]);
            const half8 bf1 = *(const half8*)(&hC[1][roff1]);
            f32x4 c3d = {0.f, 0.f, 0.f, 0.f}, c3f = {0.f, 0.f, 0.f, 0.f};
            c3d = mm(w3d0, bd0, c3d);  c3f = mm(w3f0, bf0, c3f);
            c3d = mm(w3d1, bd1, c3d);  c3f = mm(w3f1, bf1, c3f);
            od = c3d[0] + b3d;          // same value in all C rows
            of = c3f[0] + b3f;
        }

        // ---- replicated state update: paired tanh(od)/sigmoid(of), one rcp ----
        {
            const float a_d = __expf(2.0f * clamp9(od)) + 1.0f; // tanh = 1 - 2/a_d
            const float a_s = __expf(-clamp9(of)) + 1.0f;       // sigm = 1/a_s
            const float R = __builtin_amdgcn_rcpf(a_d * a_s);
            const float drift_nn = 0.5f * fmaf(-2.0f * a_s, R, 1.0f);
            const float diffu = fmaf(1.5f * a_d, R, 0.1f);
            float lvn = lv + kdt * (THETA - lv) + drift_nn * dt + diffu * dwv;
            lvn = fminf(fmaxf(lvn, -5.0f), 1.0f);
            const float d = lvn - lv;
            const float o1 = dt * d, o3 = d * d;
            // s3 += outer(s2_old, dx) + outer(g, oxx),  g = s1_old/2 + dx/6
            const float g0 = fmaf(0.5f, s1a0, c6dt);
            const float g1 = fmaf(0.5f, s1a1, (1.0f / 6.0f) * d);
            s3a0 = fmaf(s2a0, dt, fmaf(g0, o0, s3a0));
            s3a1 = fmaf(s2a0, d,  fmaf(g0, o1, s3a1));
            s3a2 = fmaf(s2a1, dt, fmaf(g0, o1, s3a2));
            s3a3 = fmaf(s2a1, d,  fmaf(g0, o3, s3a3));
            s3a4 = fmaf(s2a2, dt, fmaf(g1, o0, s3a4));
            s3a5 = fmaf(s2a2, d,  fmaf(g1, o1, s3a5));
            s3a6 = fmaf(s2a3, dt, fmaf(g1, o1, s3a6));
            s3a7 = fmaf(s2a3, d,  fmaf(g1, o3, s3a7));
            // s2 += outer(s1_old + dx/2, dx)
            const float e0 = s1a0 + hdt;
            const float e1 = fmaf(0.5f, d, s1a1);
            s2a0 = fmaf(e0, dt, s2a0);  s2a1 = fmaf(e0, d, s2a1);
            s2a2 = fmaf(e1, dt, s2a2);  s2a3 = fmaf(e1, d, s2a3);
            s1a0 += dt;  s1a1 += d;
            if (tid < 16) out[pathT + t] = __expf(lvn);   // wave 0, lanes 0-15
            lv = lvn;
        }
        // Race-freedom: hA(t+1) written post-B3(t), last hA read pre-B2(t);
        // hB(t+1) post-B1(t+1), last read pre-B3(t); hC(t+1) post-B2(t+1),
        // last read (L3) pre-B1(t+1) in every wave's program order.
    }
}

extern "C" void kernel_launch(void* const* d_in, const int* in_sizes, int n_in,
                              void* d_out, int out_size, void* d_ws, size_t ws_size,
                              hipStream_t stream) {
    const float* init_var = (const float*)d_in[0];
    const float* dtp      = (const float*)d_in[1];
    const float* dwg      = (const float*)d_in[2];
    const float* dW0 = (const float*)d_in[3];
    const float* dB0 = (const float*)d_in[4];
    const float* dW1 = (const float*)d_in[5];
    const float* dB1 = (const float*)d_in[6];
    const float* dW2 = (const float*)d_in[7];
    const float* dB2 = (const float*)d_in[8];
    const float* dW3 = (const float*)d_in[9];
    const float* dB3 = (const float*)d_in[10];
    const float* fW0 = (const float*)d_in[11];
    const float* fB0 = (const float*)d_in[12];
    const float* fW1 = (const float*)d_in[13];
    const float* fB1 = (const float*)d_in[14];
    const float* fW2 = (const float*)d_in[15];
    const float* fB2 = (const float*)d_in[16];
    const float* fW3 = (const float*)d_in[17];
    const float* fB3 = (const float*)d_in[18];
    float* out = (float*)d_out;

    sim_kernel<<<dim3(8192 / PPB), dim3(NT), 0, stream>>>(
        init_var, dtp, dwg,
        dW0, dB0, dW1, dB1, dW2, dB2, dW3, dB3,
        fW0, fB0, fW1, fB1, fW2, fB2, fW3, fB3,
        out);
}

// Round 14
// 3075.163 us; speedup vs baseline: 1.2238x; 1.2238x over previous
//
#include <hip/hip_runtime.h>

#define TSTEPS 2048
#define PPB 32          // paths per block: two 16-path groups
#define NT 512          // 8 waves: g = wv>>2 (group), ct = wv&3 (column tile)
#define KAPPA 2.72f
#define THETA -3.5f

typedef _Float16 half8 __attribute__((ext_vector_type(8)));
typedef __fp16 fp16x2 __attribute__((ext_vector_type(2)));
typedef float f32x4 __attribute__((ext_vector_type(4)));

__device__ __forceinline__ f32x4 mm(half8 a, half8 b, f32x4 c) {
    return __builtin_amdgcn_mfma_f32_16x16x32_f16(a, b, c, 0, 0, 0);
}
__device__ __forceinline__ void wsplit(float v, _Float16& h, _Float16& l) {
    h = (_Float16)v; l = (_Float16)(v - (float)h);
}
// act tanh with the 2x pre-scale folded into weights: c = 2*preact
__device__ __forceinline__ float ftanh_c(float c) {
    float e = __expf(c);
    return 1.0f - 2.0f * __builtin_amdgcn_rcpf(e + 1.0f);
}
__device__ __forceinline__ float ftanh(float x) {
    float e = __expf(2.0f * x);
    return 1.0f - 2.0f * __builtin_amdgcn_rcpf(e + 1.0f);
}
__device__ __forceinline__ float fsigm(float x) {
    float e = __expf(-x);
    return __builtin_amdgcn_rcpf(1.0f + e);
}

// LDS f16 activation rows: [row 0..15][slot 0..7][elem 0..7], slot = chunk ^ (row&7).

__global__ __launch_bounds__(NT, 2) void sim_kernel(
    const float* __restrict__ init_var, const float* __restrict__ dtp,
    const float* __restrict__ dwg,
    const float* __restrict__ dW0, const float* __restrict__ dB0,
    const float* __restrict__ dW1, const float* __restrict__ dB1,
    const float* __restrict__ dW2, const float* __restrict__ dB2,
    const float* __restrict__ dW3, const float* __restrict__ dB3,
    const float* __restrict__ fW0, const float* __restrict__ fB0,
    const float* __restrict__ fW1, const float* __restrict__ fB1,
    const float* __restrict__ fW2, const float* __restrict__ fB2,
    const float* __restrict__ fW3, const float* __restrict__ fB3,
    float* __restrict__ out)
{
    __shared__ __align__(16) _Float16 hA[2][2][1024];   // [group][mlp][..]
    __shared__ __align__(16) _Float16 hB[2][2][1024];
    __shared__ __align__(16) _Float16 hC[2][2][1024];

    const int tid  = threadIdx.x;
    const int lane = tid & 63;
    const int wv   = tid >> 6;        // 0..7
    const int g    = wv >> 2;         // path group 0/1
    const int ct   = wv & 3;          // column tile 0..3
    const int l15  = lane & 15;
    const int lg   = lane >> 4;       // 0..3
    const int col  = ct * 16 + l15;   // column this lane supplies (B) / owns (C)
    const int q    = l15 & 7;

    const int roff0 = l15 * 64 + ((lg ^ q) << 3);         // chunks 0-3 (K 0..31)
    const int roff1 = l15 * 64 + (((4 + lg) ^ q) << 3);   // chunks 4-7 (K 32..63)
    int woff[4];
#pragma unroll
    for (int r = 0; r < 4; ++r) {
        const int wrow = lg * 4 + r;
        woff[r] = wrow * 64 + ((((col >> 3) ^ (wrow & 7))) << 3) + (col & 7);
    }

    // ---------------- B-fragments (2x-scaled W0..W2): 16 half8 = 64 VGPR ----------------
    half8 bd0h, bd0l, bf0h, bf0l;
#pragma unroll
    for (int i = 0; i < 8; ++i) {
        const int idx = (lg & 1) * 8 + i;
        const float vd = (idx < 15) ? 2.0f * dW0[col * 15 + idx] : 0.f;
        const float vf = (idx < 15) ? 2.0f * fW0[col * 15 + idx] : 0.f;
        _Float16 h, l;
        wsplit(vd, h, l); bd0h[i] = h; bd0l[i] = l;
        wsplit(vf, h, l); bf0h[i] = h; bf0l[i] = l;
    }
    half8 bd1h0, bd1h1, bd2h0, bd2h1;
    half8 bf1h0, bf1h1, bf2h0, bf2h1;
#pragma unroll
    for (int i = 0; i < 8; ++i) {
        const int ka = lg * 8 + i, kb = 32 + lg * 8 + i;
        bd1h0[i] = (_Float16)(2.0f * dW1[col * 64 + ka]);
        bd1h1[i] = (_Float16)(2.0f * dW1[col * 64 + kb]);
        bd2h0[i] = (_Float16)(2.0f * dW2[col * 64 + ka]);
        bd2h1[i] = (_Float16)(2.0f * dW2[col * 64 + kb]);
        bf1h0[i] = (_Float16)(2.0f * fW1[col * 64 + ka]);
        bf1h1[i] = (_Float16)(2.0f * fW1[col * 64 + kb]);
        bf2h0[i] = (_Float16)(2.0f * fW2[col * 64 + ka]);
        bf2h1[i] = (_Float16)(2.0f * fW2[col * 64 + kb]);
    }
    // L3 A-fragments (UNSCALED w3): A[r][k] = w3[k] -> C[r][p] = od[p], no shuffles.
    half8 w3d0, w3d1, w3f0, w3f1;
#pragma unroll
    for (int i = 0; i < 8; ++i) {
        const int ka = lg * 8 + i, kb = 32 + lg * 8 + i;
        w3d0[i] = (_Float16)dW3[ka];
        w3d1[i] = (_Float16)dW3[kb];
        w3f0[i] = (_Float16)fW3[ka];
        w3f1[i] = (_Float16)fW3[kb];
    }
    // Pin weight fragments against in-loop rematerialization.
    asm volatile("" : "+v"(bd0h), "+v"(bd0l), "+v"(bf0h), "+v"(bf0l));
    asm volatile("" : "+v"(bd1h0), "+v"(bd1h1), "+v"(bd2h0), "+v"(bd2h1));
    asm volatile("" : "+v"(bf1h0), "+v"(bf1h1), "+v"(bf2h0), "+v"(bf2h1));
    asm volatile("" : "+v"(w3d0), "+v"(w3d1), "+v"(w3f0), "+v"(w3f1));

    const float biasd0 = 2.0f * dB0[col], biasd1 = 2.0f * dB1[col], biasd2 = 2.0f * dB2[col];
    const float biasf0 = 2.0f * fB0[col], biasf1 = 2.0f * fB1[col], biasf2 = 2.0f * fB2[col];
    const float b3d = dB3[0], b3f = fB3[0];
    const float dt  = dtp[0];
    const float hdt  = 0.5f * dt;
    const float c6dt = dt * (1.0f / 6.0f);
    const float kdt  = KAPPA * dt;
    const float o0   = dt * dt;

    // ---------------- replicated per-lane state (p = l15, own group) ----------------
    const int p = l15;
    const int path = blockIdx.x * PPB + (g << 4) + p;
    const size_t pathT = (size_t)path * TSTEPS;
    const float* dwp = dwg + pathT;
    float iv = fminf(fmaxf(init_var[path], 0.01f), 1.5f);
    float lv = __logf(iv);
    float s1a0 = 0.f, s1a1 = 0.f;
    float s2a0 = 0.f, s2a1 = 0.f, s2a2 = 0.f, s2a3 = 0.f;
    float s3a0 = 0.f, s3a1 = 0.f, s3a2 = 0.f, s3a3 = 0.f;
    float s3a4 = 0.f, s3a5 = 0.f, s3a6 = 0.f, s3a7 = 0.f;

    const bool selHi = (lg & 1) != 0;   // lane's L0 A-frag covers x[8..15]
    const bool selLo = (lg & 2) != 0;   // lane's L0 A-frag carries the lo split

    union H8 { half8 v; fp16x2 p2[4]; uint4 u; };

    for (int t = 0; t < TSTEPS; ++t) {
        const float dwv = dwp[t];

        // ---- build L0 A-fragment in-register (pkrtz-packed hi/lo) ----
        half8 a0;
        {
            float xv[8];
            xv[0] = selHi ? s3a2 : s1a0;
            xv[1] = selHi ? s3a3 : s1a1;
            xv[2] = selHi ? s3a4 : s2a0;
            xv[3] = selHi ? s3a5 : s2a1;
            xv[4] = selHi ? s3a6 : s2a2;
            xv[5] = selHi ? s3a7 : s2a3;
            xv[6] = selHi ? (lv + 4.0f) : s3a0;
            xv[7] = selHi ? 0.f : s3a1;
            H8 hi, lo, a;
#pragma unroll
            for (int j = 0; j < 4; ++j)
                hi.p2[j] = __builtin_amdgcn_cvt_pkrtz(xv[2 * j], xv[2 * j + 1]);
#pragma unroll
            for (int j = 0; j < 4; ++j) {
                const float r0 = xv[2 * j]     - (float)hi.p2[j][0];
                const float r1 = xv[2 * j + 1] - (float)hi.p2[j][1];
                lo.p2[j] = __builtin_amdgcn_cvt_pkrtz(r0, r1);
            }
            a.u.x = selLo ? lo.u.x : hi.u.x;
            a.u.y = selLo ? lo.u.y : hi.u.y;
            a.u.z = selLo ? lo.u.z : hi.u.z;
            a.u.w = selLo ? lo.u.w : hi.u.w;
            a0 = a.v;
        }

        // ---- L0: x -> h0 (both MLPs, 2 MFMA each; C = 2*preact) ----
        {
            f32x4 cd = {biasd0, biasd0, biasd0, biasd0};
            f32x4 cf = {biasf0, biasf0, biasf0, biasf0};
            cd = mm(a0, bd0h, cd);  cf = mm(a0, bf0h, cf);
            cd = mm(a0, bd0l, cd);  cf = mm(a0, bf0l, cf);
#pragma unroll
            for (int r = 0; r < 4; ++r) {
                hA[g][0][woff[r]] = (_Float16)ftanh_c(cd[r]);
                hA[g][1][woff[r]] = (_Float16)ftanh_c(cf[r]);
            }
        }
        __syncthreads();

        // ---- L1: h0 -> h1 ----
        {
            const half8 ad0 = *(const half8*)(&hA[g][0][roff0]);
            const half8 ad1 = *(const half8*)(&hA[g][0][roff1]);
            const half8 af0 = *(const half8*)(&hA[g][1][roff0]);
            const half8 af1 = *(const half8*)(&hA[g][1][roff1]);
            f32x4 cd = {biasd1, biasd1, biasd1, biasd1};
            f32x4 cf = {biasf1, biasf1, biasf1, biasf1};
            cd = mm(ad0, bd1h0, cd);  cf = mm(af0, bf1h0, cf);
            cd = mm(ad1, bd1h1, cd);  cf = mm(af1, bf1h1, cf);
#pragma unroll
            for (int r = 0; r < 4; ++r) {
                hB[g][0][woff[r]] = (_Float16)ftanh_c(cd[r]);
                hB[g][1][woff[r]] = (_Float16)ftanh_c(cf[r]);
            }
        }
        __syncthreads();

        // ---- L2: h1 -> h2 ----
        {
            const half8 ad0 = *(const half8*)(&hB[g][0][roff0]);
            const half8 ad1 = *(const half8*)(&hB[g][0][roff1]);
            const half8 af0 = *(const half8*)(&hB[g][1][roff0]);
            const half8 af1 = *(const half8*)(&hB[g][1][roff1]);
            f32x4 cd = {biasd2, biasd2, biasd2, biasd2};
            f32x4 cf = {biasf2, biasf2, biasf2, biasf2};
            cd = mm(ad0, bd2h0, cd);  cf = mm(af0, bf2h0, cf);
            cd = mm(ad1, bd2h1, cd);  cf = mm(af1, bf2h1, cf);
#pragma unroll
            for (int r = 0; r < 4; ++r) {
                hC[g][0][woff[r]] = (_Float16)ftanh_c(cd[r]);
                hC[g][1][woff[r]] = (_Float16)ftanh_c(cf[r]);
            }
        }
        __syncthreads();

        // ---- L3: od/of broadcast to all lanes via w3-replicated A ----
        float od, of;
        {
            const half8 bd0 = *(const half8*)(&hC[g][0][roff0]);
            const half8 bd1 = *(const half8*)(&hC[g][0][roff1]);
            const half8 bf0 = *(const half8*)(&hC[g][1][roff0]);
            const half8 bf1 = *(const half8*)(&hC[g][1][roff1]);
            f32x4 c3d = {0.f, 0.f, 0.f, 0.f}, c3f = {0.f, 0.f, 0.f, 0.f};
            c3d = mm(w3d0, bd0, c3d);  c3f = mm(w3f0, bf0, c3f);
            c3d = mm(w3d1, bd1, c3d);  c3f = mm(w3f1, bf1, c3f);
            od = c3d[0] + b3d;          // same value in all C rows
            of = c3f[0] + b3f;
        }

        // ---- replicated state update (all lanes, own group, p = l15) ----
        {
            const float drift_nn = 0.5f * ftanh(od);
            const float diffu = fmaf(1.5f, fsigm(of), 0.1f);
            float lvn = lv + kdt * (THETA - lv) + drift_nn * dt + diffu * dwv;
            lvn = fminf(fmaxf(lvn, -5.0f), 1.0f);
            const float d = lvn - lv;
            const float o1 = dt * d, o3 = d * d;
            const float g0 = fmaf(0.5f, s1a0, c6dt);
            const float g1 = fmaf(0.5f, s1a1, (1.0f / 6.0f) * d);
            s3a0 = fmaf(s2a0, dt, fmaf(g0, o0, s3a0));
            s3a1 = fmaf(s2a0, d,  fmaf(g0, o1, s3a1));
            s3a2 = fmaf(s2a1, dt, fmaf(g0, o1, s3a2));
            s3a3 = fmaf(s2a1, d,  fmaf(g0, o3, s3a3));
            s3a4 = fmaf(s2a2, dt, fmaf(g1, o0, s3a4));
            s3a5 = fmaf(s2a2, d,  fmaf(g1, o1, s3a5));
            s3a6 = fmaf(s2a3, dt, fmaf(g1, o1, s3a6));
            s3a7 = fmaf(s2a3, d,  fmaf(g1, o3, s3a7));
            const float e0 = s1a0 + hdt;
            const float e1 = fmaf(0.5f, d, s1a1);
            s2a0 = fmaf(e0, dt, s2a0);  s2a1 = fmaf(e0, d, s2a1);
            s2a2 = fmaf(e1, dt, s2a2);  s2a3 = fmaf(e1, d, s2a3);
            s1a0 += dt;  s1a1 += d;
            if ((ct == 0) && lane < 16) out[pathT + t] = __expf(lvn); // waves 0 & 4
            lv = lvn;
        }
        // Race-freedom (per group; barriers are block-wide): hA(t+1) written
        // post-B3(t), last read pre-B2(t); hB(t+1) post-B1(t+1), last read
        // pre-B3(t); hC(t+1) post-B2(t+1), last read (L3) pre-B1(t+1).
    }
}

extern "C" void kernel_launch(void* const* d_in, const int* in_sizes, int n_in,
                              void* d_out, int out_size, void* d_ws, size_t ws_size,
                              hipStream_t stream) {
    const float* init_var = (const float*)d_in[0];
    const float* dtp      = (const float*)d_in[1];
    const float* dwg      = (const float*)d_in[2];
    const float* dW0 = (const float*)d_in[3];
    const float* dB0 = (const float*)d_in[4];
    const float* dW1 = (const float*)d_in[5];
    const float* dB1 = (const float*)d_in[6];
    const float* dW2 = (const float*)d_in[7];
    const float* dB2 = (const float*)d_in[8];
    const float* dW3 = (const float*)d_in[9];
    const float* dB3 = (const float*)d_in[10];
    const float* fW0 = (const float*)d_in[11];
    const float* fB0 = (const float*)d_in[12];
    const float* fW1 = (const float*)d_in[13];
    const float* fB1 = (const float*)d_in[14];
    const float* fW2 = (const float*)d_in[15];
    const float* fB2 = (const float*)d_in[16];
    const float* fW3 = (const float*)d_in[17];
    const float* fB3 = (const float*)d_in[18];
    float* out = (float*)d_out;

    sim_kernel<<<dim3(8192 / PPB), dim3(NT), 0, stream>>>(
        init_var, dtp, dwg,
        dW0, dB0, dW1, dB1, dW2, dB2, dW3, dB3,
        fW0, fB0, fW1, fB1, fW2, fB2, fW3, fB3,
        out);
}

// Round 17
// 2864.104 us; speedup vs baseline: 1.3140x; 1.0737x over previous
//
#include <hip/hip_runtime.h>

#define TSTEPS 2048
#define PPB 32          // paths per block: two 16-path groups
#define NT 512          // 8 waves: g = wv>>2 (group), ct = wv&3 (column tile)
#define KAPPA 2.72f
#define THETA -3.5f
#define SCL 2.8853900817779268f      // 2*log2(e): tanh pre-scale folded into weights
#define LOG2E 1.4426950408889634f

// exp2 via compiler-visible intrinsic (backend handles TRANS hazards).
// Fallback = e^{ln2 x} through __expf (proven path, one extra mul).
#if __has_builtin(__builtin_amdgcn_exp2f)
#define EXP2(x) __builtin_amdgcn_exp2f(x)
#else
#define EXP2(x) __expf(0.6931471805599453f * (x))
#endif

typedef _Float16 half8 __attribute__((ext_vector_type(8)));
typedef __fp16 fp16x2 __attribute__((ext_vector_type(2)));
typedef float f32x4 __attribute__((ext_vector_type(4)));

__device__ __forceinline__ f32x4 mm(half8 a, half8 b, f32x4 c) {
    return __builtin_amdgcn_mfma_f32_16x16x32_f16(a, b, c, 0, 0, 0);
}
__device__ __forceinline__ void wsplit(float v, _Float16& h, _Float16& l) {
    h = (_Float16)v; l = (_Float16)(v - (float)h);
}
// tanh with SCL pre-folded: c = 2*log2e*preact; tanh = 1 - 2/(2^c + 1)
__device__ __forceinline__ float tanh_c(float c) {
    return 1.0f - 2.0f * __builtin_amdgcn_rcpf(EXP2(c) + 1.0f);
}

// LDS f16 activation rows: [row 0..15][slot 0..7][elem 0..7], slot = chunk ^ (row&7).

__global__ __launch_bounds__(NT, 2) void sim_kernel(
    const float* __restrict__ init_var, const float* __restrict__ dtp,
    const float* __restrict__ dwg,
    const float* __restrict__ dW0, const float* __restrict__ dB0,
    const float* __restrict__ dW1, const float* __restrict__ dB1,
    const float* __restrict__ dW2, const float* __restrict__ dB2,
    const float* __restrict__ dW3, const float* __restrict__ dB3,
    const float* __restrict__ fW0, const float* __restrict__ fB0,
    const float* __restrict__ fW1, const float* __restrict__ fB1,
    const float* __restrict__ fW2, const float* __restrict__ fB2,
    const float* __restrict__ fW3, const float* __restrict__ fB3,
    float* __restrict__ out)
{
    __shared__ __align__(16) _Float16 hA[2][2][1024];   // [group][mlp][..]
    __shared__ __align__(16) _Float16 hB[2][2][1024];
    __shared__ __align__(16) _Float16 hC[2][2][1024];

    const int tid  = threadIdx.x;
    const int lane = tid & 63;
    const int wv   = tid >> 6;        // 0..7
    const int g    = wv >> 2;         // path group 0/1
    const int ct   = wv & 3;          // column tile 0..3
    const int l15  = lane & 15;
    const int lg   = lane >> 4;       // 0..3
    const int col  = ct * 16 + l15;   // column this lane supplies (B) / owns (C)
    const int q    = l15 & 7;

    const int roff0 = l15 * 64 + ((lg ^ q) << 3);         // chunks 0-3 (K 0..31)
    const int roff1 = l15 * 64 + (((4 + lg) ^ q) << 3);   // chunks 4-7 (K 32..63)
    int woff[4];
#pragma unroll
    for (int r = 0; r < 4; ++r) {
        const int wrow = lg * 4 + r;
        woff[r] = wrow * 64 + ((((col >> 3) ^ (wrow & 7))) << 3) + (col & 7);
    }

    // ---------------- B-fragments (SCL-scaled W0..W2): 16 half8 = 64 VGPR ----------------
    half8 bd0h, bd0l, bf0h, bf0l;
#pragma unroll
    for (int i = 0; i < 8; ++i) {
        const int idx = (lg & 1) * 8 + i;
        const float vd = (idx < 15) ? SCL * dW0[col * 15 + idx] : 0.f;
        const float vf = (idx < 15) ? SCL * fW0[col * 15 + idx] : 0.f;
        _Float16 h, l;
        wsplit(vd, h, l); bd0h[i] = h; bd0l[i] = l;
        wsplit(vf, h, l); bf0h[i] = h; bf0l[i] = l;
    }
    half8 bd1h0, bd1h1, bd2h0, bd2h1;
    half8 bf1h0, bf1h1, bf2h0, bf2h1;
#pragma unroll
    for (int i = 0; i < 8; ++i) {
        const int ka = lg * 8 + i, kb = 32 + lg * 8 + i;
        bd1h0[i] = (_Float16)(SCL * dW1[col * 64 + ka]);
        bd1h1[i] = (_Float16)(SCL * dW1[col * 64 + kb]);
        bd2h0[i] = (_Float16)(SCL * dW2[col * 64 + ka]);
        bd2h1[i] = (_Float16)(SCL * dW2[col * 64 + kb]);
        bf1h0[i] = (_Float16)(SCL * fW1[col * 64 + ka]);
        bf1h1[i] = (_Float16)(SCL * fW1[col * 64 + kb]);
        bf2h0[i] = (_Float16)(SCL * fW2[col * 64 + ka]);
        bf2h1[i] = (_Float16)(SCL * fW2[col * 64 + kb]);
    }
    // L3 A-fragments: w3d scaled by SCL (tanh pre-fold), w3f by -log2e (sigmoid pre-fold).
    half8 w3d0, w3d1, w3f0, w3f1;
#pragma unroll
    for (int i = 0; i < 8; ++i) {
        const int ka = lg * 8 + i, kb = 32 + lg * 8 + i;
        w3d0[i] = (_Float16)(SCL * dW3[ka]);
        w3d1[i] = (_Float16)(SCL * dW3[kb]);
        w3f0[i] = (_Float16)(-LOG2E * fW3[ka]);
        w3f1[i] = (_Float16)(-LOG2E * fW3[kb]);
    }
    // Pin weight fragments against in-loop rematerialization.
    asm volatile("" : "+v"(bd0h), "+v"(bd0l), "+v"(bf0h), "+v"(bf0l));
    asm volatile("" : "+v"(bd1h0), "+v"(bd1h1), "+v"(bd2h0), "+v"(bd2h1));
    asm volatile("" : "+v"(bf1h0), "+v"(bf1h1), "+v"(bf2h0), "+v"(bf2h1));
    asm volatile("" : "+v"(w3d0), "+v"(w3d1), "+v"(w3f0), "+v"(w3f1));

    const float biasd0 = SCL * dB0[col], biasd1 = SCL * dB1[col], biasd2 = SCL * dB2[col];
    const float biasf0 = SCL * fB0[col], biasf1 = SCL * fB1[col], biasf2 = SCL * fB2[col];
    const float b3ds = SCL * dB3[0];        // scaled drift bias (seeds L3 C)
    const float b3fs = -LOG2E * fB3[0];     // scaled diff bias
    const float dt  = dtp[0];
    const float hdt  = 0.5f * dt;
    const float c6dt = dt * (1.0f / 6.0f);
    const float kdt  = KAPPA * dt;
    const float o0   = dt * dt;

    // ---------------- replicated per-lane state (p = l15, own group) ----------------
    const int p = l15;
    const int path = blockIdx.x * PPB + (g << 4) + p;
    const size_t pathT = (size_t)path * TSTEPS;
    const float* dwp = dwg + pathT;
    float iv = fminf(fmaxf(init_var[path], 0.01f), 1.5f);
    float lv = __logf(iv);
    float s1a0 = 0.f, s1a1 = 0.f;
    float s2a0 = 0.f, s2a1 = 0.f, s2a2 = 0.f, s2a3 = 0.f;
    float s3a0 = 0.f, s3a1 = 0.f, s3a2 = 0.f, s3a3 = 0.f;
    float s3a4 = 0.f, s3a5 = 0.f, s3a6 = 0.f, s3a7 = 0.f;

    const bool selHi = (lg & 1) != 0;   // lane's L0 A-frag covers x[8..15]
    const bool selLo = (lg & 2) != 0;   // lane's L0 A-frag carries the lo split

    union H8 { half8 v; fp16x2 p2[4]; uint4 u; };

    for (int t = 0; t < TSTEPS; ++t) {
        const float dwv = dwp[t];

        // ---- build L0 A-fragment in-register (pkrtz-packed hi/lo) ----
        half8 a0;
        {
            float xv[8];
            xv[0] = selHi ? s3a2 : s1a0;
            xv[1] = selHi ? s3a3 : s1a1;
            xv[2] = selHi ? s3a4 : s2a0;
            xv[3] = selHi ? s3a5 : s2a1;
            xv[4] = selHi ? s3a6 : s2a2;
            xv[5] = selHi ? s3a7 : s2a3;
            xv[6] = selHi ? (lv + 4.0f) : s3a0;
            xv[7] = selHi ? 0.f : s3a1;
            H8 hi, lo, a;
#pragma unroll
            for (int j = 0; j < 4; ++j)
                hi.p2[j] = __builtin_amdgcn_cvt_pkrtz(xv[2 * j], xv[2 * j + 1]);
#pragma unroll
            for (int j = 0; j < 4; ++j) {
                const float r0 = xv[2 * j]     - (float)hi.p2[j][0];
                const float r1 = xv[2 * j + 1] - (float)hi.p2[j][1];
                lo.p2[j] = __builtin_amdgcn_cvt_pkrtz(r0, r1);
            }
            a.u.x = selLo ? lo.u.x : hi.u.x;
            a.u.y = selLo ? lo.u.y : hi.u.y;
            a.u.z = selLo ? lo.u.z : hi.u.z;
            a.u.w = selLo ? lo.u.w : hi.u.w;
            a0 = a.v;
        }

        // ---- L0: x -> h0 (both MLPs, 2 MFMA each; C = SCL*preact) ----
        {
            f32x4 cd = {biasd0, biasd0, biasd0, biasd0};
            f32x4 cf = {biasf0, biasf0, biasf0, biasf0};
            cd = mm(a0, bd0h, cd);  cf = mm(a0, bf0h, cf);
            cd = mm(a0, bd0l, cd);  cf = mm(a0, bf0l, cf);
#pragma unroll
            for (int r = 0; r < 4; ++r) {
                hA[g][0][woff[r]] = (_Float16)tanh_c(cd[r]);
                hA[g][1][woff[r]] = (_Float16)tanh_c(cf[r]);
            }
        }
        __syncthreads();

        // ---- L1: h0 -> h1 ----
        {
            const half8 ad0 = *(const half8*)(&hA[g][0][roff0]);
            const half8 ad1 = *(const half8*)(&hA[g][0][roff1]);
            const half8 af0 = *(const half8*)(&hA[g][1][roff0]);
            const half8 af1 = *(const half8*)(&hA[g][1][roff1]);
            f32x4 cd = {biasd1, biasd1, biasd1, biasd1};
            f32x4 cf = {biasf1, biasf1, biasf1, biasf1};
            cd = mm(ad0, bd1h0, cd);  cf = mm(af0, bf1h0, cf);
            cd = mm(ad1, bd1h1, cd);  cf = mm(af1, bf1h1, cf);
#pragma unroll
            for (int r = 0; r < 4; ++r) {
                hB[g][0][woff[r]] = (_Float16)tanh_c(cd[r]);
                hB[g][1][woff[r]] = (_Float16)tanh_c(cf[r]);
            }
        }
        __syncthreads();

        // ---- L2: h1 -> h2 ----
        {
            const half8 ad0 = *(const half8*)(&hB[g][0][roff0]);
            const half8 ad1 = *(const half8*)(&hB[g][0][roff1]);
            const half8 af0 = *(const half8*)(&hB[g][1][roff0]);
            const half8 af1 = *(const half8*)(&hB[g][1][roff1]);
            f32x4 cd = {biasd2, biasd2, biasd2, biasd2};
            f32x4 cf = {biasf2, biasf2, biasf2, biasf2};
            cd = mm(ad0, bd2h0, cd);  cf = mm(af0, bf2h0, cf);
            cd = mm(ad1, bd2h1, cd);  cf = mm(af1, bf2h1, cf);
#pragma unroll
            for (int r = 0; r < 4; ++r) {
                hC[g][0][woff[r]] = (_Float16)tanh_c(cd[r]);
                hC[g][1][woff[r]] = (_Float16)tanh_c(cf[r]);
            }
        }
        __syncthreads();

        // ---- L3: od'/of' broadcast via w3-replicated A; bias pre-seeded in C ----
        float odc, ofc;
        {
            const half8 bd0 = *(const half8*)(&hC[g][0][roff0]);
            const half8 bd1 = *(const half8*)(&hC[g][0][roff1]);
            const half8 bf0 = *(const half8*)(&hC[g][1][roff0]);
            const half8 bf1 = *(const half8*)(&hC[g][1][roff1]);
            f32x4 c3d = {b3ds, b3ds, b3ds, b3ds};
            f32x4 c3f = {b3fs, b3fs, b3fs, b3fs};
            c3d = mm(w3d0, bd0, c3d);  c3f = mm(w3f0, bf0, c3f);
            c3d = mm(w3d1, bd1, c3d);  c3f = mm(w3f1, bf1, c3f);
            odc = c3d[0];   // = SCL * od       (same value in all C rows)
            ofc = c3f[0];   // = -log2e * of
        }

        // ---- replicated state update (all lanes, own group, p = l15) ----
        {
            // drift tanh: pre-scaled input; sigmoid: sig(of) = 1/(1+2^(-log2e*of))
            const float drift_nn = 0.5f * (1.0f - 2.0f * __builtin_amdgcn_rcpf(EXP2(odc) + 1.0f));
            const float diffu = fmaf(1.5f, __builtin_amdgcn_rcpf(1.0f + EXP2(ofc)), 0.1f);
            float lvn = lv + kdt * (THETA - lv) + drift_nn * dt + diffu * dwv;
            lvn = fminf(fmaxf(lvn, -5.0f), 1.0f);
            const float d = lvn - lv;
            const float o1 = dt * d, o3 = d * d;
            const float g0 = fmaf(0.5f, s1a0, c6dt);
            const float g1 = fmaf(0.5f, s1a1, (1.0f / 6.0f) * d);
            s3a0 = fmaf(s2a0, dt, fmaf(g0, o0, s3a0));
            s3a1 = fmaf(s2a0, d,  fmaf(g0, o1, s3a1));
            s3a2 = fmaf(s2a1, dt, fmaf(g0, o1, s3a2));
            s3a3 = fmaf(s2a1, d,  fmaf(g0, o3, s3a3));
            s3a4 = fmaf(s2a2, dt, fmaf(g1, o0, s3a4));
            s3a5 = fmaf(s2a2, d,  fmaf(g1, o1, s3a5));
            s3a6 = fmaf(s2a3, dt, fmaf(g1, o1, s3a6));
            s3a7 = fmaf(s2a3, d,  fmaf(g1, o3, s3a7));
            const float e0 = s1a0 + hdt;
            const float e1 = fmaf(0.5f, d, s1a1);
            s2a0 = fmaf(e0, dt, s2a0);  s2a1 = fmaf(e0, d, s2a1);
            s2a2 = fmaf(e1, dt, s2a2);  s2a3 = fmaf(e1, d, s2a3);
            s1a0 += dt;  s1a1 += d;
            if ((ct == 0) && lane < 16) out[pathT + t] = __expf(lvn); // waves 0 & 4
            lv = lvn;
        }
        // Race-freedom (per group; barriers are block-wide): hA(t+1) written
        // post-B3(t), last read pre-B2(t); hB(t+1) post-B1(t+1), last read
        // pre-B3(t); hC(t+1) post-B2(t+1), last read (L3) pre-B1(t+1).
    }
}

extern "C" void kernel_launch(void* const* d_in, const int* in_sizes, int n_in,
                              void* d_out, int out_size, void* d_ws, size_t ws_size,
                              hipStream_t stream) {
    const float* init_var = (const float*)d_in[0];
    const float* dtp      = (const float*)d_in[1];
    const float* dwg      = (const float*)d_in[2];
    const float* dW0 = (const float*)d_in[3];
    const float* dB0 = (const float*)d_in[4];
    const float* dW1 = (const float*)d_in[5];
    const float* dB1 = (const float*)d_in[6];
    const float* dW2 = (const float*)d_in[7];
    const float* dB2 = (const float*)d_in[8];
    const float* dW3 = (const float*)d_in[9];
    const float* dB3 = (const float*)d_in[10];
    const float* fW0 = (const float*)d_in[11];
    const float* fB0 = (const float*)d_in[12];
    const float* fW1 = (const float*)d_in[13];
    const float* fB1 = (const float*)d_in[14];
    const float* fW2 = (const float*)d_in[15];
    const float* fB2 = (const float*)d_in[16];
    const float* fW3 = (const float*)d_in[17];
    const float* fB3 = (const float*)d_in[18];
    float* out = (float*)d_out;

    sim_kernel<<<dim3(8192 / PPB), dim3(NT), 0, stream>>>(
        init_var, dtp, dwg,
        dW0, dB0, dW1, dB1, dW2, dB2, dW3, dB3,
        fW0, fB0, fW1, fB1, fW2, fB2, fW3, fB3,
        out);
}

// Round 18
// 2733.747 us; speedup vs baseline: 1.3767x; 1.0477x over previous
//
#include <hip/hip_runtime.h>

#define TSTEPS 2048
#define PPB 32          // paths per block: two 16-path groups
#define NT 512          // 8 waves: g = wv>>2 (group), ct = wv&3 (hidden column tile)
#define KAPPA 2.72f
#define THETA -3.5f
#define SCL 2.8853900817779268f      // 2*log2(e): tanh pre-scale folded into weights
#define LOG2E 1.4426950408889634f

#if __has_builtin(__builtin_amdgcn_exp2f)
#define EXP2(x) __builtin_amdgcn_exp2f(x)
#else
#define EXP2(x) __expf(0.6931471805599453f * (x))
#endif

typedef _Float16 half8 __attribute__((ext_vector_type(8)));
typedef __fp16 fp16x2 __attribute__((ext_vector_type(2)));
typedef float f32x4 __attribute__((ext_vector_type(4)));

__device__ __forceinline__ f32x4 mm(half8 a, half8 b, f32x4 c) {
    return __builtin_amdgcn_mfma_f32_16x16x32_f16(a, b, c, 0, 0, 0);
}
__device__ __forceinline__ void wsplit(float v, _Float16& h, _Float16& l) {
    h = (_Float16)v; l = (_Float16)(v - (float)h);
}
// tanh with SCL pre-folded: c = 2*log2e*preact; tanh = 1 - 2/(2^c + 1)
__device__ __forceinline__ float tanh_c(float c) {
    return 1.0f - 2.0f * __builtin_amdgcn_rcpf(EXP2(c) + 1.0f);
}

// LDS f16 activation rows: [path 0..15][slot 0..7][elem 0..7], slot = chunk ^ (path&7).

__global__ __launch_bounds__(NT, 2) void sim_kernel(
    const float* __restrict__ init_var, const float* __restrict__ dtp,
    const float* __restrict__ dwg,
    const float* __restrict__ dW0, const float* __restrict__ dB0,
    const float* __restrict__ dW1, const float* __restrict__ dB1,
    const float* __restrict__ dW2, const float* __restrict__ dB2,
    const float* __restrict__ dW3, const float* __restrict__ dB3,
    const float* __restrict__ fW0, const float* __restrict__ fB0,
    const float* __restrict__ fW1, const float* __restrict__ fB1,
    const float* __restrict__ fW2, const float* __restrict__ fB2,
    const float* __restrict__ fW3, const float* __restrict__ fB3,
    float* __restrict__ out)
{
    __shared__ __align__(16) _Float16 hA[2][2][1024];   // [group][mlp][..]
    __shared__ __align__(16) _Float16 hB[2][2][1024];
    __shared__ __align__(16) _Float16 hC[2][2][1024];

    const int tid  = threadIdx.x;
    const int lane = tid & 63;
    const int wv   = tid >> 6;        // 0..7
    const int g    = wv >> 2;         // path group 0/1
    const int ct   = wv & 3;          // hidden column tile 0..3
    const int l15  = lane & 15;
    const int lg   = lane >> 4;       // 0..3
    const int col  = ct * 16 + l15;   // hidden unit this lane's weight frag serves (A row)
    const int q    = l15 & 7;

    // activation reads (B-frag: col=l15=path, k=hidden chunk):
    const int roff0 = l15 * 64 + ((lg ^ q) << 3);         // hidden 0..31
    const int roff1 = l15 * 64 + (((4 + lg) ^ q) << 3);   // hidden 32..63
    // C^T write: lane owns path=l15 (C col), hidden = ct*16 + lg*4 + r (C rows)
    // -> 4 contiguous f16 in [path][hidden] layout, one b64 store.
    const int wchunk = ct * 2 + (lg >> 1);
    const int woffp  = l15 * 64 + ((wchunk ^ q) << 3) + (lg & 1) * 4;

    // ---------------- weight fragments (serve as MFMA *A* operands now) ----------------
    half8 bd0h, bd0l, bf0h, bf0l;
#pragma unroll
    for (int i = 0; i < 8; ++i) {
        const int idx = (lg & 1) * 8 + i;
        const float vd = (idx < 15) ? SCL * dW0[col * 15 + idx] : 0.f;
        const float vf = (idx < 15) ? SCL * fW0[col * 15 + idx] : 0.f;
        _Float16 h, l;
        wsplit(vd, h, l); bd0h[i] = h; bd0l[i] = l;
        wsplit(vf, h, l); bf0h[i] = h; bf0l[i] = l;
    }
    half8 bd1h0, bd1h1, bd2h0, bd2h1;
    half8 bf1h0, bf1h1, bf2h0, bf2h1;
#pragma unroll
    for (int i = 0; i < 8; ++i) {
        const int ka = lg * 8 + i, kb = 32 + lg * 8 + i;
        bd1h0[i] = (_Float16)(SCL * dW1[col * 64 + ka]);
        bd1h1[i] = (_Float16)(SCL * dW1[col * 64 + kb]);
        bd2h0[i] = (_Float16)(SCL * dW2[col * 64 + ka]);
        bd2h1[i] = (_Float16)(SCL * dW2[col * 64 + kb]);
        bf1h0[i] = (_Float16)(SCL * fW1[col * 64 + ka]);
        bf1h1[i] = (_Float16)(SCL * fW1[col * 64 + kb]);
        bf2h0[i] = (_Float16)(SCL * fW2[col * 64 + ka]);
        bf2h1[i] = (_Float16)(SCL * fW2[col * 64 + kb]);
    }
    // L3 A-fragments: w3d scaled by SCL (tanh pre-fold), w3f by -log2e (sigmoid pre-fold).
    half8 w3d0, w3d1, w3f0, w3f1;
#pragma unroll
    for (int i = 0; i < 8; ++i) {
        const int ka = lg * 8 + i, kb = 32 + lg * 8 + i;
        w3d0[i] = (_Float16)(SCL * dW3[ka]);
        w3d1[i] = (_Float16)(SCL * dW3[kb]);
        w3f0[i] = (_Float16)(-LOG2E * fW3[ka]);
        w3f1[i] = (_Float16)(-LOG2E * fW3[kb]);
    }
    // Per-row bias vectors (C rows = hidden now): rows ct*16+lg*4 .. +3
    const int hrow = ct * 16 + lg * 4;
    f32x4 bd0v, bd1v, bd2v, bf0v, bf1v, bf2v;
#pragma unroll
    for (int r = 0; r < 4; ++r) {
        bd0v[r] = SCL * dB0[hrow + r];  bf0v[r] = SCL * fB0[hrow + r];
        bd1v[r] = SCL * dB1[hrow + r];  bf1v[r] = SCL * fB1[hrow + r];
        bd2v[r] = SCL * dB2[hrow + r];  bf2v[r] = SCL * fB2[hrow + r];
    }
    // Pin loop-invariant fragments against in-loop rematerialization.
    asm volatile("" : "+v"(bd0h), "+v"(bd0l), "+v"(bf0h), "+v"(bf0l));
    asm volatile("" : "+v"(bd1h0), "+v"(bd1h1), "+v"(bd2h0), "+v"(bd2h1));
    asm volatile("" : "+v"(bf1h0), "+v"(bf1h1), "+v"(bf2h0), "+v"(bf2h1));
    asm volatile("" : "+v"(w3d0), "+v"(w3d1), "+v"(w3f0), "+v"(w3f1));
    asm volatile("" : "+v"(bd0v), "+v"(bd1v), "+v"(bd2v));
    asm volatile("" : "+v"(bf0v), "+v"(bf1v), "+v"(bf2v));

    const float b3ds = SCL * dB3[0];
    const float b3fs = -LOG2E * fB3[0];
    const float dt  = dtp[0];
    const float hdt  = 0.5f * dt;
    const float c6dt = dt * (1.0f / 6.0f);
    const float kdt  = KAPPA * dt;
    const float o0   = dt * dt;

    // ---------------- replicated per-lane state (p = l15, own group) ----------------
    const int p = l15;
    const int path = blockIdx.x * PPB + (g << 4) + p;
    const size_t pathT = (size_t)path * TSTEPS;
    const float* dwp = dwg + pathT;
    float iv = fminf(fmaxf(init_var[path], 0.01f), 1.5f);
    float lv = __logf(iv);
    float s1a0 = 0.f, s1a1 = 0.f;
    float s2a0 = 0.f, s2a1 = 0.f, s2a2 = 0.f, s2a3 = 0.f;
    float s3a0 = 0.f, s3a1 = 0.f, s3a2 = 0.f, s3a3 = 0.f;
    float s3a4 = 0.f, s3a5 = 0.f, s3a6 = 0.f, s3a7 = 0.f;

    const bool selHi = (lg & 1) != 0;   // lane's x-frag covers x[8..15]
    const bool selLo = (lg & 2) != 0;   // lane's x-frag carries the lo split

    union H8 { half8 v; fp16x2 p2[4]; uint4 u; };
    union Pk { fp16x2 p2[2]; uint2 u; };

    for (int t = 0; t < TSTEPS; ++t) {
        const float dwv = dwp[t];

        // ---- build x B-fragment in-register (pkrtz-packed hi/lo) ----
        half8 a0;
        {
            float xv[8];
            xv[0] = selHi ? s3a2 : s1a0;
            xv[1] = selHi ? s3a3 : s1a1;
            xv[2] = selHi ? s3a4 : s2a0;
            xv[3] = selHi ? s3a5 : s2a1;
            xv[4] = selHi ? s3a6 : s2a2;
            xv[5] = selHi ? s3a7 : s2a3;
            xv[6] = selHi ? (lv + 4.0f) : s3a0;
            xv[7] = selHi ? 0.f : s3a1;
            H8 hi, lo, a;
#pragma unroll
            for (int j = 0; j < 4; ++j)
                hi.p2[j] = __builtin_amdgcn_cvt_pkrtz(xv[2 * j], xv[2 * j + 1]);
#pragma unroll
            for (int j = 0; j < 4; ++j) {
                const float r0 = xv[2 * j]     - (float)hi.p2[j][0];
                const float r1 = xv[2 * j + 1] - (float)hi.p2[j][1];
                lo.p2[j] = __builtin_amdgcn_cvt_pkrtz(r0, r1);
            }
            a.u.x = selLo ? lo.u.x : hi.u.x;
            a.u.y = selLo ? lo.u.y : hi.u.y;
            a.u.z = selLo ? lo.u.z : hi.u.z;
            a.u.w = selLo ? lo.u.w : hi.u.w;
            a0 = a.v;
        }

        // ---- L0: x -> h0 (C^T: A=W0, B=x; rows=hidden, cols=path) ----
        {
            f32x4 cd = bd0v, cf = bf0v;
            cd = mm(bd0h, a0, cd);  cf = mm(bf0h, a0, cf);
            cd = mm(bd0l, a0, cd);  cf = mm(bf0l, a0, cf);
            Pk pd, pf;
            pd.p2[0] = __builtin_amdgcn_cvt_pkrtz(tanh_c(cd[0]), tanh_c(cd[1]));
            pd.p2[1] = __builtin_amdgcn_cvt_pkrtz(tanh_c(cd[2]), tanh_c(cd[3]));
            pf.p2[0] = __builtin_amdgcn_cvt_pkrtz(tanh_c(cf[0]), tanh_c(cf[1]));
            pf.p2[1] = __builtin_amdgcn_cvt_pkrtz(tanh_c(cf[2]), tanh_c(cf[3]));
            *(uint2*)(&hA[g][0][woffp]) = pd.u;
            *(uint2*)(&hA[g][1][woffp]) = pf.u;
        }
        __syncthreads();

        // ---- L1: h0 -> h1 ----
        {
            const half8 ad0 = *(const half8*)(&hA[g][0][roff0]);
            const half8 ad1 = *(const half8*)(&hA[g][0][roff1]);
            const half8 af0 = *(const half8*)(&hA[g][1][roff0]);
            const half8 af1 = *(const half8*)(&hA[g][1][roff1]);
            f32x4 cd = bd1v, cf = bf1v;
            cd = mm(bd1h0, ad0, cd);  cf = mm(bf1h0, af0, cf);
            cd = mm(bd1h1, ad1, cd);  cf = mm(bf1h1, af1, cf);
            Pk pd, pf;
            pd.p2[0] = __builtin_amdgcn_cvt_pkrtz(tanh_c(cd[0]), tanh_c(cd[1]));
            pd.p2[1] = __builtin_amdgcn_cvt_pkrtz(tanh_c(cd[2]), tanh_c(cd[3]));
            pf.p2[0] = __builtin_amdgcn_cvt_pkrtz(tanh_c(cf[0]), tanh_c(cf[1]));
            pf.p2[1] = __builtin_amdgcn_cvt_pkrtz(tanh_c(cf[2]), tanh_c(cf[3]));
            *(uint2*)(&hB[g][0][woffp]) = pd.u;
            *(uint2*)(&hB[g][1][woffp]) = pf.u;
        }
        __syncthreads();

        // ---- L2: h1 -> h2 ----
        {
            const half8 ad0 = *(const half8*)(&hB[g][0][roff0]);
            const half8 ad1 = *(const half8*)(&hB[g][0][roff1]);
            const half8 af0 = *(const half8*)(&hB[g][1][roff0]);
            const half8 af1 = *(const half8*)(&hB[g][1][roff1]);
            f32x4 cd = bd2v, cf = bf2v;
            cd = mm(bd2h0, ad0, cd);  cf = mm(bf2h0, af0, cf);
            cd = mm(bd2h1, ad1, cd);  cf = mm(bf2h1, af1, cf);
            Pk pd, pf;
            pd.p2[0] = __builtin_amdgcn_cvt_pkrtz(tanh_c(cd[0]), tanh_c(cd[1]));
            pd.p2[1] = __builtin_amdgcn_cvt_pkrtz(tanh_c(cd[2]), tanh_c(cd[3]));
            pf.p2[0] = __builtin_amdgcn_cvt_pkrtz(tanh_c(cf[0]), tanh_c(cf[1]));
            pf.p2[1] = __builtin_amdgcn_cvt_pkrtz(tanh_c(cf[2]), tanh_c(cf[3]));
            *(uint2*)(&hC[g][0][woffp]) = pd.u;
            *(uint2*)(&hC[g][1][woffp]) = pf.u;
        }
        __syncthreads();

        // ---- L3: od'/of' broadcast via w3-replicated A; bias pre-seeded in C ----
        float odc, ofc;
        {
            const half8 bd0 = *(const half8*)(&hC[g][0][roff0]);
            const half8 bd1 = *(const half8*)(&hC[g][0][roff1]);
            const half8 bf0 = *(const half8*)(&hC[g][1][roff0]);
            const half8 bf1 = *(const half8*)(&hC[g][1][roff1]);
            f32x4 c3d = {b3ds, b3ds, b3ds, b3ds};
            f32x4 c3f = {b3fs, b3fs, b3fs, b3fs};
            c3d = mm(w3d0, bd0, c3d);  c3f = mm(w3f0, bf0, c3f);
            c3d = mm(w3d1, bd1, c3d);  c3f = mm(w3f1, bf1, c3f);
            odc = c3d[0];   // = SCL * od       (same value in all C rows)
            ofc = c3f[0];   // = -log2e * of
        }

        // ---- replicated state update (all lanes, own group, p = l15) ----
        {
            const float drift_nn = 0.5f * (1.0f - 2.0f * __builtin_amdgcn_rcpf(EXP2(odc) + 1.0f));
            const float diffu = fmaf(1.5f, __builtin_amdgcn_rcpf(1.0f + EXP2(ofc)), 0.1f);
            float lvn = lv + kdt * (THETA - lv) + drift_nn * dt + diffu * dwv;
            lvn = fminf(fmaxf(lvn, -5.0f), 1.0f);
            const float d = lvn - lv;
            const float o1 = dt * d, o3 = d * d;
            const float g0 = fmaf(0.5f, s1a0, c6dt);
            const float g1 = fmaf(0.5f, s1a1, (1.0f / 6.0f) * d);
            s3a0 = fmaf(s2a0, dt, fmaf(g0, o0, s3a0));
            s3a1 = fmaf(s2a0, d,  fmaf(g0, o1, s3a1));
            s3a2 = fmaf(s2a1, dt, fmaf(g0, o1, s3a2));
            s3a3 = fmaf(s2a1, d,  fmaf(g0, o3, s3a3));
            s3a4 = fmaf(s2a2, dt, fmaf(g1, o0, s3a4));
            s3a5 = fmaf(s2a2, d,  fmaf(g1, o1, s3a5));
            s3a6 = fmaf(s2a3, dt, fmaf(g1, o1, s3a6));
            s3a7 = fmaf(s2a3, d,  fmaf(g1, o3, s3a7));
            const float e0 = s1a0 + hdt;
            const float e1 = fmaf(0.5f, d, s1a1);
            s2a0 = fmaf(e0, dt, s2a0);  s2a1 = fmaf(e0, d, s2a1);
            s2a2 = fmaf(e1, dt, s2a2);  s2a3 = fmaf(e1, d, s2a3);
            s1a0 += dt;  s1a1 += d;
            if ((ct == 0) && lane < 16) out[pathT + t] = __expf(lvn); // waves 0 & 4
            lv = lvn;
        }
        // Race-freedom (per group; barriers are block-wide): hA(t+1) written
        // post-B3(t), last read pre-B2(t); hB(t+1) post-B1(t+1), last read
        // pre-B3(t); hC(t+1) post-B2(t+1), last read (L3) pre-B1(t+1).
    }
}

extern "C" void kernel_launch(void* const* d_in, const int* in_sizes, int n_in,
                              void* d_out, int out_size, void* d_ws, size_t ws_size,
                              hipStream_t stream) {
    const float* init_var = (const float*)d_in[0];
    const float* dtp      = (const float*)d_in[1];
    const float* dwg      = (const float*)d_in[2];
    const float* dW0 = (const float*)d_in[3];
    const float* dB0 = (const float*)d_in[4];
    const float* dW1 = (const float*)d_in[5];
    const float* dB1 = (const float*)d_in[6];
    const float* dW2 = (const float*)d_in[7];
    const float* dB2 = (const float*)d_in[8];
    const float* dW3 = (const float*)d_in[9];
    const float* dB3 = (const float*)d_in[10];
    const float* fW0 = (const float*)d_in[11];
    const float* fB0 = (const float*)d_in[12];
    const float* fW1 = (const float*)d_in[13];
    const float* fB1 = (const float*)d_in[14];
    const float* fW2 = (const float*)d_in[15];
    const float* fB2 = (const float*)d_in[16];
    const float* fW3 = (const float*)d_in[17];
    const float* fB3 = (const float*)d_in[18];
    float* out = (float*)d_out;

    sim_kernel<<<dim3(8192 / PPB), dim3(NT), 0, stream>>>(
        init_var, dtp, dwg,
        dW0, dB0, dW1, dB1, dW2, dB2, dW3, dB3,
        fW0, fB0, fW1, fB1, fW2, fB2, fW3, fB3,
        out);
}